// Round 12
// baseline (226.765 us; speedup 1.0000x reference)
//
#include <hip/hip_runtime.h>
#include <hip/hip_fp8.h>
#include <math.h>

#define NB 4096
#define IN_D 230
#define DM 256
#define NL 12
#define DST 16
#define DI 512
#define DTR 16
#define XPN 48
#define XB 520    // xcs/szs row stride (bytes)
#define HB 264    // hs row stride (bytes)

typedef __attribute__((ext_vector_type(4))) float floatx4;
typedef __attribute__((ext_vector_type(2))) long long2v;
typedef __attribute__((ext_vector_type(4))) int intx4;

// fast device math (range-reduced exactness unnecessary: values are tiny)
__device__ __forceinline__ float silu_f(float x) {
    return x * __builtin_amdgcn_rcpf(1.0f + __expf(-x));
}
__device__ __forceinline__ float softplus_f(float x) {
    return (x > 20.0f) ? x : __logf(1.0f + __expf(x));
}

// HW fp8 e4m3 converts (gfx950 = OCP), guarded fallback
__device__ __forceinline__ unsigned char f2fp8(float x) {
#if __has_builtin(__builtin_amdgcn_cvt_pk_fp8_f32)
    return (unsigned char)(__builtin_amdgcn_cvt_pk_fp8_f32(x, x, 0, false) & 0xff);
#else
    __hip_fp8_e4m3 t(x); return (unsigned char)t.__x;
#endif
}
__device__ __forceinline__ float fp82f(unsigned char b) {
#if __has_builtin(__builtin_amdgcn_cvt_f32_fp8)
    return __builtin_amdgcn_cvt_f32_fp8((int)b, 0);
#else
    __hip_fp8_e4m3 t; t.__x = (__hip_fp8_storage_t)b; return (float)t;
#endif
}

// ---------- conversion kernels (once per call) ----------

// x [4096 x 230] fp32 -> xpad [4096 x 256] fp8 (zero-padded K, row-major)
__global__ __launch_bounds__(256) void conv_x(const float* __restrict__ x, unsigned char* __restrict__ xp) {
    int idx = blockIdx.x * 256 + threadIdx.x;
    int r = idx >> 8, k = idx & 255;
    float v = (k < IN_D) ? x[(size_t)r * IN_D + k] : 0.0f;
    xp[idx] = f2fp8(v);
}

// src [K x N] fp32 -> dst packed fp8 fragment-major (1KB per 16col x 64K chunk).
// LDS-staged: coalesced 64-wide reads, transpose in LDS, one 16B store per thread.
// grid = (Kp/64, Np/64, L). Same dst layout as R10's conv_wt_pack.
__global__ __launch_bounds__(256) void conv_wt_pack(const float* __restrict__ src0, unsigned char* __restrict__ dst0,
                                                    int K, int N, int Kp, int Np) {
    const float* src = src0 + (size_t)blockIdx.z * K * N;
    unsigned char* dst = dst0 + (size_t)blockIdx.z * Np * Kp;
    __shared__ float t[64][65];
    const int g = blockIdx.x;          // k-group of 64
    const int nb = blockIdx.y;         // n-block of 64
    const int k0 = g * 64, n0 = nb * 64;
    const int r = threadIdx.x >> 6, c = threadIdx.x & 63;
#pragma unroll
    for (int i = 0; i < 16; i++) {
        int kk = k0 + i * 4 + r;
        int nn = n0 + c;
        t[i * 4 + r][c] = (kk < K && nn < N) ? src[(size_t)kk * N + nn] : 0.0f;
    }
    __syncthreads();
    const int cbi = threadIdx.x >> 6;  // local 16-col chunk 0..3
    const int lane = threadIdx.x & 63;
    const int q = lane >> 4, m16 = lane & 15;
    const int ngroups = Kp >> 6;
    const int chunk = (nb * 4 + cbi) * ngroups + g;
    union { unsigned char b[16]; intx4 v; } buf;
#pragma unroll
    for (int sub = 0; sub < 2; sub++)
#pragma unroll
        for (int byt = 0; byt < 8; byt++) {
            int k = sub * 32 + q * 8 + byt;        // within group
            int n = cbi * 16 + m16;                // within tile
            buf.b[sub * 8 + byt] = f2fp8(t[k][n]);
        }
    *(intx4*)(dst + (size_t)chunk * 1024 + lane * 16) = buf.v;
}

// dt_w [NL][16][512] fp32 -> packed fp8 B-fragments, K=16 padded to 32 (small; plain)
__global__ __launch_bounds__(256) void conv_dtw_pack(const float* __restrict__ src, unsigned char* __restrict__ dst) {
    int l = blockIdx.y;
    int idx = blockIdx.x * 256 + threadIdx.x;             // over 32*512 = 16384
    int chunk = idx >> 9;
    int r = idx & 511;
    int lane = r >> 3, byt = r & 7;
    int q = lane >> 4, m16 = lane & 15;
    int col = chunk * 16 + m16;
    int k = q * 8 + byt;
    float v = (k < DTR) ? src[(size_t)l * DTR * DI + (size_t)k * DI + col] : 0.0f;
    dst[(size_t)l * 16384 + idx] = f2fp8(v);
}

// ---------- the whole network, fused: 256 wgs x 16 rows, 1024 threads, fp8, packed weights ----------
__global__ __launch_bounds__(1024) void mamba_all(
    const unsigned char* __restrict__ xpad, const unsigned char* __restrict__ WiT,
    const float* __restrict__ bi,
    const unsigned char* __restrict__ ipT, const unsigned char* __restrict__ opT,
    const unsigned char* __restrict__ xpT, const unsigned char* __restrict__ dtwP,
    const float* __restrict__ conv_w, const float* __restrict__ conv_b,
    const float* __restrict__ dt_b, const float* __restrict__ Dp,
    const float* __restrict__ Wo, const float* __restrict__ bo,
    float* __restrict__ out)
{
    __shared__ unsigned char hs[16 * HB];    // h (16 x 256) fp8
    __shared__ unsigned char xcs[16 * XB];   // xc, then y in place, fp8
    __shared__ unsigned char szs[16 * XB];   // silu(z) fp8
    __shared__ float dbls[16 * 68];
    __shared__ float sbc[16];

    const int tid = threadIdx.x;
    const int w = tid >> 6, lane = tid & 63;
    const int q = lane >> 4, m16 = lane & 15;
    const int rb = blockIdx.x * 16;

    // stage 0: h = xpad @ Wi + bi   (wave w: col-blk w; Wi packed, Kp=256 -> 4 groups)
    {
        floatx4 a0 = (floatx4){0.f, 0.f, 0.f, 0.f};
        floatx4 a1 = (floatx4){0.f, 0.f, 0.f, 0.f};
        const unsigned char* Ap = xpad + (size_t)(rb + m16) * DM + q * 8;
        const unsigned char* Bp = WiT + (size_t)(w * 4) * 1024 + lane * 16;
#pragma unroll
        for (int g = 0; g < 4; g++) {
            long2v b = *(const long2v*)(Bp + g * 1024);
            long av0 = *(const long*)(Ap + (g * 2) * 32);
            long av1 = *(const long*)(Ap + (g * 2 + 1) * 32);
            a0 = __builtin_amdgcn_mfma_f32_16x16x32_fp8_fp8(av0, b.x, a0, 0, 0, 0);
            a1 = __builtin_amdgcn_mfma_f32_16x16x32_fp8_fp8(av1, b.y, a1, 0, 0, 0);
        }
        a0 = a0 + a1;
        int col = w * 16 + m16;
#pragma unroll
        for (int r = 0; r < 4; r++)
            hs[(q * 4 + r) * HB + col] = f2fp8(a0[r] + bi[col]);
    }
    __syncthreads();

    for (int l = 0; l < NL; l++) {
        const unsigned char* ip = ipT + (size_t)l * 2 * DI * DM;
        const unsigned char* xp = xpT + (size_t)l * 64 * DI;
        const unsigned char* op = opT + (size_t)l * DM * DI;
        const unsigned char* dwp = dtwP + (size_t)l * 16384;
        const float* cw = conv_w + (size_t)l * DI * 4;
        const float* cb = conv_b + (size_t)l * DI;
        const float* db = dt_b + (size_t)l * DI;
        const float* Dv = Dp + (size_t)l * DI;

        // stage 1: xz = h @ in_proj  (wave w: col-blks w*4..w*4+3; Kp=256 -> 4 groups)
        {
            floatx4 acc[4];
#pragma unroll
            for (int t = 0; t < 4; t++) acc[t] = (floatx4){0.f, 0.f, 0.f, 0.f};
            const unsigned char* Bp = ip + (size_t)(w * 16) * 1024 + lane * 16;
            const unsigned char* Ar = hs + m16 * HB + q * 8;
#pragma unroll
            for (int g = 0; g < 4; g++) {
                long a0 = *(const long*)(Ar + (g * 2) * 32);
                long a1 = *(const long*)(Ar + (g * 2 + 1) * 32);
                long2v b[4];
#pragma unroll
                for (int t = 0; t < 4; t++)
                    b[t] = *(const long2v*)(Bp + (t * 4 + g) * 1024);
#pragma unroll
                for (int t = 0; t < 4; t++)
                    acc[t] = __builtin_amdgcn_mfma_f32_16x16x32_fp8_fp8(a0, b[t].x, acc[t], 0, 0, 0);
#pragma unroll
                for (int t = 0; t < 4; t++)
                    acc[t] = __builtin_amdgcn_mfma_f32_16x16x32_fp8_fp8(a1, b[t].y, acc[t], 0, 0, 0);
            }
            if (w < 8) {
#pragma unroll
                for (int t = 0; t < 4; t++)
#pragma unroll
                    for (int r = 0; r < 4; r++) {
                        int col = w * 64 + t * 16 + m16;
                        float v = silu_f(acc[t][r] * cw[col * 4 + 3] + cb[col]);
                        xcs[(q * 4 + r) * XB + col] = f2fp8(v);
                    }
            } else {
#pragma unroll
                for (int t = 0; t < 4; t++)
#pragma unroll
                    for (int r = 0; r < 4; r++) {
                        int col = (w - 8) * 64 + t * 16 + m16;
                        szs[(q * 4 + r) * XB + col] = f2fp8(silu_f(acc[t][r]));
                    }
            }
        }
        __syncthreads();

        // stage 2: dbl = xc @ x_proj  (waves 0..3: col-blk w; Kp=512 -> 8 groups)
        if (w < 4) {
            floatx4 a0 = (floatx4){0.f, 0.f, 0.f, 0.f};
            floatx4 a1 = (floatx4){0.f, 0.f, 0.f, 0.f};
            const unsigned char* Bp = xp + (size_t)(w * 8) * 1024 + lane * 16;
            const unsigned char* Ar = xcs + m16 * XB + q * 8;
#pragma unroll
            for (int g = 0; g < 8; g++) {
                long2v b = *(const long2v*)(Bp + g * 1024);
                long av0 = *(const long*)(Ar + (g * 2) * 32);
                long av1 = *(const long*)(Ar + (g * 2 + 1) * 32);
                a0 = __builtin_amdgcn_mfma_f32_16x16x32_fp8_fp8(av0, b.x, a0, 0, 0, 0);
                a1 = __builtin_amdgcn_mfma_f32_16x16x32_fp8_fp8(av1, b.y, a1, 0, 0, 0);
            }
            a0 = a0 + a1;
#pragma unroll
            for (int r = 0; r < 4; r++)
                dbls[(q * 4 + r) * 68 + w * 16 + m16] = a0[r];
        }
        __syncthreads();

        // hoisted stage-3 loads (independent of dbls; overlap with bc + barrier)
        const unsigned char* Wp = dwp + (size_t)(w * 2) * 512 + lane * 8;
        long b0 = *(const long*)(Wp);
        long b1 = *(const long*)(Wp + 512);
        const int c0 = w * 32 + m16, c1 = c0 + 16;
        const float db0 = db[c0], db1 = db[c1];
        const float dv0 = Dv[c0], dv1 = Dv[c1];

        // bc[row] = dbl[row,16:32].dbl[row,32:48]
        if (tid < 256) {
            int row = tid >> 4, s = tid & 15;
            float p = dbls[row * 68 + DTR + s] * dbls[row * 68 + DTR + DST + s];
            p += __shfl_xor(p, 1);
            p += __shfl_xor(p, 2);
            p += __shfl_xor(p, 4);
            p += __shfl_xor(p, 8);
            if (s == 0) sbc[row] = p;
        }
        __syncthreads();

        // stage 3 (MFMA): dt = softplus(dbl[:,0:16] @ dtw + db); y = (dt*bc + D)*xc*sz
        {
            long afrag = 0;
            if (q < 2) {
                const float* dr = &dbls[m16 * 68 + q * 8];
                unsigned lo, hi;
                lo = __builtin_amdgcn_cvt_pk_fp8_f32(dr[0], dr[1], 0, false);
                lo = __builtin_amdgcn_cvt_pk_fp8_f32(dr[2], dr[3], lo, true);
                hi = __builtin_amdgcn_cvt_pk_fp8_f32(dr[4], dr[5], 0, false);
                hi = __builtin_amdgcn_cvt_pk_fp8_f32(dr[6], dr[7], hi, true);
                union { unsigned u[2]; long l; } av;
                av.u[0] = lo; av.u[1] = hi;
                afrag = av.l;
            }
            floatx4 d0v = (floatx4){db0, db0, db0, db0};
            floatx4 d1v = (floatx4){db1, db1, db1, db1};
            d0v = __builtin_amdgcn_mfma_f32_16x16x32_fp8_fp8(afrag, b0, d0v, 0, 0, 0);
            d1v = __builtin_amdgcn_mfma_f32_16x16x32_fp8_fp8(afrag, b1, d1v, 0, 0, 0);
#pragma unroll
            for (int r = 0; r < 4; r++) {
                int row = q * 4 + r;
                float bcv = sbc[row];
                int off0 = row * XB + c0;
                float v0 = (softplus_f(d0v[r]) * bcv + dv0) * fp82f(xcs[off0]) * fp82f(szs[off0]);
                xcs[off0] = f2fp8(v0);
                int off1 = off0 + 16;
                float v1 = (softplus_f(d1v[r]) * bcv + dv1) * fp82f(xcs[off1]) * fp82f(szs[off1]);
                xcs[off1] = f2fp8(v1);
            }
        }
        __syncthreads();

        // stage 4: h = y @ out_proj  (wave w: col-blk w; Kp=512 -> 8 groups)
        {
            floatx4 a0 = (floatx4){0.f, 0.f, 0.f, 0.f};
            floatx4 a1 = (floatx4){0.f, 0.f, 0.f, 0.f};
            const unsigned char* Bp = op + (size_t)(w * 8) * 1024 + lane * 16;
            const unsigned char* Ar = xcs + m16 * XB + q * 8;
#pragma unroll
            for (int g = 0; g < 8; g++) {
                long2v b = *(const long2v*)(Bp + g * 1024);
                long av0 = *(const long*)(Ar + (g * 2) * 32);
                long av1 = *(const long*)(Ar + (g * 2 + 1) * 32);
                a0 = __builtin_amdgcn_mfma_f32_16x16x32_fp8_fp8(av0, b.x, a0, 0, 0, 0);
                a1 = __builtin_amdgcn_mfma_f32_16x16x32_fp8_fp8(av1, b.y, a1, 0, 0, 0);
            }
            a0 = a0 + a1;
            int col = w * 16 + m16;
#pragma unroll
            for (int r = 0; r < 4; r++)
                hs[(q * 4 + r) * HB + col] = f2fp8(a0[r]);
        }
        __syncthreads();
    }

    // final: wave w reduces row w
    {
        float s = 0.0f;
#pragma unroll
        for (int j = 0; j < 4; j++)
            s += fp82f(hs[w * HB + lane * 4 + j]) * Wo[lane * 4 + j];
#pragma unroll
        for (int off = 32; off > 0; off >>= 1) s += __shfl_down(s, off);
        if (lane == 0) out[rb + w] = s + bo[0];
    }
}

extern "C" void kernel_launch(void* const* d_in, const int* in_sizes, int n_in,
                              void* d_out, int out_size, void* d_ws, size_t ws_size,
                              hipStream_t stream)
{
    const float* x       = (const float*)d_in[0];
    const float* Wi      = (const float*)d_in[1];
    const float* bi      = (const float*)d_in[2];
    const float* in_proj = (const float*)d_in[3];
    const float* conv_w  = (const float*)d_in[4];
    const float* conv_b  = (const float*)d_in[5];
    const float* x_proj  = (const float*)d_in[6];
    const float* dt_w    = (const float*)d_in[7];
    const float* dt_b    = (const float*)d_in[8];
    // d_in[9] = A_log: dead (L==1, h0==0)
    const float* Dp      = (const float*)d_in[10];
    const float* out_pw  = (const float*)d_in[11];
    const float* Wo      = (const float*)d_in[12];
    const float* bo      = (const float*)d_in[13];

    unsigned char* ws = (unsigned char*)d_ws;
    unsigned char* xpad = ws;                              // 4096*256
    unsigned char* WiT  = xpad + (size_t)NB * DM;          // 256*256
    unsigned char* ipT  = WiT + (size_t)DM * DM;           // 12*1024*256
    unsigned char* opT  = ipT + (size_t)NL * 2 * DI * DM;  // 12*256*512
    unsigned char* xpT  = opT + (size_t)NL * DM * DI;      // 12*64*512
    unsigned char* dtwP = xpT + (size_t)NL * 64 * DI;      // 12*16384 fp8 fragments

    dim3 blk(256);

    conv_x<<<dim3(NB * DM / 256), blk, 0, stream>>>(x, xpad);
    conv_wt_pack<<<dim3(4, 4, 1), blk, 0, stream>>>(Wi, WiT, IN_D, DM, DM, DM);
    conv_wt_pack<<<dim3(4, 16, NL), blk, 0, stream>>>(in_proj, ipT, DM, 2 * DI, DM, 2 * DI);
    conv_wt_pack<<<dim3(8, 4, NL), blk, 0, stream>>>(out_pw, opT, DI, DM, DI, DM);
    conv_wt_pack<<<dim3(8, 1, NL), blk, 0, stream>>>(x_proj, xpT, DI, XPN, DI, 64);
    conv_dtw_pack<<<dim3(64, NL), blk, 0, stream>>>(dt_w, dtwP);

    mamba_all<<<dim3(NB / 16), dim3(1024), 0, stream>>>(
        xpad, WiT, bi, ipT, opT, xpT, dtwP,
        conv_w, conv_b, dt_b, Dp, Wo, bo, (float*)d_out);
}